// Round 7
// baseline (223.425 us; speedup 1.0000x reference)
//
#include <hip/hip_runtime.h>
#include <math.h>

// Problem constants (from reference setup_inputs)
#define BB 128        // batch
#define NN 2000       // nodes
#define EE 20000      // edges
#define CC 16         // channels
#define FUNC_LO 200   // func nodes: [200, 1800)
#define FUNC_HI 1800
#define OUT_LO 1800   // output nodes: [1800, 2000)
#define NFUNC 1600
#define EPSV 1e-5f
#define SS 40         // fixed slots per node per direction (Poisson(10): P(deg>40)~1e-15)
#define HP 129        // padded LDS stride
#define NPB 2         // nodes per block
#define NBLK (NFUNC / NPB)   // 800 blocks
#define TPB (128 * NPB)      // 256 threads

// ---------------- prep: slot assign + operand gather + transpose + zero out ---------
// One thread per edge does its own atomic slot-claim then immediately writes the
// gathered operands (slot value depends only on atomics among edges sharing a node;
// all other writes are thread-local -> single kernel, no internal dependencies).
__global__ __launch_bounds__(256) void k_prep(
    const float* __restrict__ x, const int* __restrict__ ei,
    const float* __restrict__ w1, const float* __restrict__ w3,
    const float* __restrict__ b3,
    int* __restrict__ degIn, int* __restrict__ degOut,
    int* __restrict__ posIn,
    float* __restrict__ xT, float* __restrict__ w1s, float* __restrict__ w3s,
    float* __restrict__ b3s, int* __restrict__ inoff, int* __restrict__ wout,
    int* __restrict__ dstn, float* __restrict__ out)
{
    int t = blockIdx.x * 256 + threadIdx.x;   // grid = NN*BB = 256000 threads
    if (t < EE) {
        int s = ei[t], d = ei[EE + t];
        int p = atomicAdd(&degIn[d], 1);
        int q = atomicAdd(&degOut[s], 1);
        int pi = d * SS + p, po = s * SS + q;
        posIn[t] = pi;
        inoff[pi] = s * BB;          // layer-0 input row = xT[src]
        wout[po]  = pi * BB;         // write target row = dst's in-slot
        dstn[po]  = d;
        b3s[po]   = b3[t];
        const float4* w1r = (const float4*)(w1 + (size_t)t * CC);
        float4*       w1d = (float4*)(w1s + (size_t)pi * CC);
        const float4* w3r = (const float4*)(w3 + (size_t)t * CC);
        float4*       w3d = (float4*)(w3s + (size_t)po * CC);
        #pragma unroll
        for (int i = 0; i < 4; i++) { w1d[i] = w1r[i]; w3d[i] = w3r[i]; }
    }
    if (t < NN * BB) {
        int b = t / NN, n = t - b * NN;
        xT[n * BB + b] = x[t];       // transpose x (B,N) -> xT (N,B), coalesced read
        out[t] = 0.0f;               // final output: zero everywhere (atomics add later)
    }
}

// ---------------- batchnorm + elu over a per-thread register column ----------------
// Thread b owns t[c] = h[c][b] for one node. Stats per channel over 128 b via LDS.
// Both node-halves of the block call this the same number of times -> barrier-safe.
__device__ __forceinline__ void bn_elu(float (&t)[CC],
                                       const float* __restrict__ g,
                                       const float* __restrict__ be,
                                       float* tile, float* part_s, float* part_ss,
                                       float* sc, float* sh, int b) {
    #pragma unroll
    for (int c = 0; c < CC; c++) tile[c * HP + b] = t[c];
    __syncthreads();
    {
        int c = b & 15, grp = b >> 4;          // 16 channels x 8 groups of 16 b
        float s = 0.f, ss = 0.f;
        #pragma unroll
        for (int i = 0; i < 16; i++) {
            float v = tile[c * HP + grp * 16 + i];
            s += v; ss += v * v;
        }
        part_s[grp * 16 + c] = s;
        part_ss[grp * 16 + c] = ss;
    }
    __syncthreads();
    if (b < CC) {
        float S = 0.f, SSm = 0.f;
        #pragma unroll
        for (int g8 = 0; g8 < 8; g8++) { S += part_s[g8 * 16 + b]; SSm += part_ss[g8 * 16 + b]; }
        float mean = S * (1.0f / BB);
        float var = SSm * (1.0f / BB) - mean * mean;
        float scale = rsqrtf(var + EPSV) * g[b];
        sc[b] = scale;
        sh[b] = be[b] - mean * scale;
    }
    __syncthreads();
    #pragma unroll
    for (int c = 0; c < CC; c++) {
        float u = t[c] * sc[c] + sh[c];
        t[c] = (u > 0.0f) ? u : (__expf(u) - 1.0f);
    }
}

// ---------------- one layer for one func node (one 128-thread half-block) ----------
__device__ __forceinline__ void layer_body(
    const float* __restrict__ xe_in, const int* __restrict__ inoff, // inoff: layer 0 only
    const float* __restrict__ xT,
    const float* __restrict__ w1s, const float* __restrict__ w2,
    const float* __restrict__ w3s, const float* __restrict__ b3s,
    const int* __restrict__ wout, const int* __restrict__ dstn,
    const float* __restrict__ g1, const float* __restrict__ be1,
    const float* __restrict__ g2, const float* __restrict__ be2,
    const int* __restrict__ degIn, const int* __restrict__ degOut,
    float* __restrict__ xe_out, float* __restrict__ out, int lastFlag,
    float* tile, float* part_s, float* part_ss, float* sc, float* sh,
    int n, int b)
{
    const int base = n * SS;
    int dIn = degIn[n];                  // wave-uniform -> s_load
    int dOut = degOut[n];
    float x0r = xT[n * BB + b];

    // ---- Phase A: weighted segment-sum over in-slots (8 loads in flight) ----
    float a[CC];
    #pragma unroll
    for (int c = 0; c < CC; c++) a[c] = 0.0f;

    for (int k0 = 0; k0 < dIn; k0 += 8) {
        float v[8];
        #pragma unroll
        for (int j = 0; j < 8; j++) {
            v[j] = 0.0f;
            if (k0 + j < dIn) {          // uniform predicate
                int ro = inoff ? inoff[base + k0 + j] : (base + k0 + j) * BB;
                v[j] = xe_in[ro + b];    // coalesced 512B row
            }
        }
        #pragma unroll
        for (int j = 0; j < 8; j++) {
            if (k0 + j < dIn) {
                const float* wr = &w1s[(size_t)(base + k0 + j) * CC]; // uniform -> s_load
                #pragma unroll
                for (int c = 0; c < CC; c++) a[c] += v[j] * wr[c];
            }
        }
    }

    // ---- bn1 + elu ----
    bn_elu(a, g1 + n * CC, be1 + n * CC, tile, part_s, part_ss, sc, sh, b);

    // ---- 16x16 matmul from registers, wave-uniform weights ----
    float h2[CC];
    #pragma unroll
    for (int d = 0; d < CC; d++) h2[d] = 0.0f;
    const float* w2n = w2 + n * (CC * CC);
    #pragma unroll
    for (int c = 0; c < CC; c++) {
        float av = a[c];
        #pragma unroll
        for (int d = 0; d < CC; d++) h2[d] += av * w2n[c * CC + d];
    }

    // ---- bn2 + elu ----
    bn_elu(h2, g2 + n * CC, be2 + n * CC, tile, part_s, part_ss, sc, sh, b);

    // ---- Phase C: push to live out-slots ----
    for (int q0 = 0; q0 < dOut; q0 += 4) {
        #pragma unroll
        for (int j = 0; j < 4; j++) {
            int q = q0 + j;
            if (q >= dOut) break;        // uniform
            int sl = base + q;
            int dn = dstn[sl];
            bool live = lastFlag ? (dn >= OUT_LO) : (dn >= FUNC_LO && dn < FUNC_HI);
            if (!live) continue;         // uniform: dead rows never read
            const float* wr = &w3s[(size_t)sl * CC];   // uniform -> s_load
            float val = b3s[sl] + x0r;
            #pragma unroll
            for (int d = 0; d < CC; d++) val += h2[d] * wr[d];
            if (lastFlag) atomicAdd(&out[(size_t)b * NN + dn], val);
            else          xe_out[wout[sl] + b] = val;
        }
    }
}

// ---------------- constant rows for non-func-src edges (grid-stride) ----------------
// These rows are b3[e]+x0[e] at EVERY layer: write once into both xe buffers; edges
// landing on output nodes contribute straight into the final output.
__device__ __forceinline__ void fill_body(const int* __restrict__ ei,
    const int* __restrict__ posIn, const float* __restrict__ b3,
    const float* __restrict__ xT, float* __restrict__ xeA, float* __restrict__ xeB,
    float* __restrict__ out, int gtid, int gsize)
{
    for (int t = gtid; t < EE * BB; t += gsize) {
        int e = t >> 7, bb = t & 127;
        int s = ei[e];
        if (s >= FUNC_LO && s < FUNC_HI) continue;   // func src: handled by layers
        int d = ei[EE + e];
        float val = b3[e] + xT[s * BB + bb];
        if (d >= FUNC_LO && d < FUNC_HI) {
            int ro = posIn[e] * BB;
            xeA[ro + bb] = val;
            xeB[ro + bb] = val;
        } else if (d >= OUT_LO) {
            atomicAdd(&out[(size_t)bb * NN + d], val);
        }
    }
}

// ---------------- one stage per launch: (optional fill) + one layer ----------------
__global__ __launch_bounds__(TPB) void k_stage(
    const int* __restrict__ ei, const int* __restrict__ posIn,
    const float* __restrict__ b3,
    const float* __restrict__ xe_in, const int* __restrict__ inoff,
    const float* __restrict__ xT,
    const float* __restrict__ w1s, const float* __restrict__ w2,
    const float* __restrict__ w3s, const float* __restrict__ b3s,
    const int* __restrict__ wout, const int* __restrict__ dstn,
    const float* __restrict__ g1, const float* __restrict__ be1,
    const float* __restrict__ g2, const float* __restrict__ be2,
    const int* __restrict__ degIn, const int* __restrict__ degOut,
    float* __restrict__ xeA, float* __restrict__ xeB,
    float* __restrict__ xe_out, float* __restrict__ out, int lastFlag, int doFill)
{
    __shared__ float tile[NPB][CC * HP];
    __shared__ float part_s[NPB][128], part_ss[NPB][128];
    __shared__ float sc[NPB][CC], sh[NPB][CC];

    const int tid = threadIdx.x;
    const int half = tid >> 7;
    const int b = tid & 127;
    const int n = FUNC_LO + blockIdx.x * NPB + half;   // wave-uniform

    if (doFill)
        fill_body(ei, posIn, b3, xT, xeA, xeB, out, blockIdx.x * TPB + tid, NBLK * TPB);

    layer_body(xe_in, inoff, xT, w1s, w2, w3s, b3s, wout, dstn, g1, be1, g2, be2,
               degIn, degOut, xe_out, out, lastFlag,
               tile[half], part_s[half], part_ss[half], sc[half], sh[half], n, b);
}

extern "C" void kernel_launch(void* const* d_in, const int* in_sizes, int n_in,
                              void* d_out, int out_size, void* d_ws, size_t ws_size,
                              hipStream_t stream) {
    const float* x   = (const float*)d_in[0];
    const float* w1  = (const float*)d_in[1];
    // d_in[2] = b1: cancels through batchnorm
    const float* w2  = (const float*)d_in[3];
    // d_in[4] = b2: cancels through batchnorm
    const float* w3  = (const float*)d_in[5];
    const float* b3  = (const float*)d_in[6];
    const float* g1  = (const float*)d_in[7];
    const float* be1 = (const float*)d_in[8];
    const float* g2  = (const float*)d_in[9];
    const float* be2 = (const float*)d_in[10];
    const int* ei    = (const int*)d_in[11];
    float* out = (float*)d_out;

    // workspace partition (fixed-stride slot layout, S=40) — ~95 MB total
    char* ws = (char*)d_ws;
    float* xT   = (float*)ws;  ws += (size_t)NN * BB * 4;            // 1.0 MB
    float* xeA  = (float*)ws;  ws += (size_t)NN * SS * BB * 4;       // 41 MB
    float* xeB  = (float*)ws;  ws += (size_t)NN * SS * BB * 4;       // 41 MB
    float* w1s  = (float*)ws;  ws += (size_t)NN * SS * CC * 4;       // 5.1 MB
    float* w3s  = (float*)ws;  ws += (size_t)NN * SS * CC * 4;       // 5.1 MB
    float* b3s  = (float*)ws;  ws += (size_t)NN * SS * 4;
    int* degIn  = (int*)ws;    ws += (size_t)NN * 4;                 // contiguous pair
    int* degOut = (int*)ws;    ws += (size_t)NN * 4;                 //   (one memset)
    int* posIn  = (int*)ws;    ws += (size_t)EE * 4;
    int* inoff  = (int*)ws;    ws += (size_t)NN * SS * 4;
    int* wout   = (int*)ws;    ws += (size_t)NN * SS * 4;
    int* dstn   = (int*)ws;    ws += (size_t)NN * SS * 4;

    hipMemsetAsync(degIn, 0, 2 * NN * sizeof(int), stream);
    k_prep<<<(NN * BB) / 256, 256, 0, stream>>>(x, ei, w1, w3, b3, degIn, degOut,
                                                posIn, xT, w1s, w3s, b3s,
                                                inoff, wout, dstn, out);

    const int* nullp = nullptr;
    k_stage<<<NBLK, TPB, 0, stream>>>(ei, posIn, b3, xT, inoff, xT, w1s, w2, w3s, b3s,
                                      wout, dstn, g1, be1, g2, be2, degIn, degOut,
                                      xeA, xeB, xeA, out, 0, 1);
    k_stage<<<NBLK, TPB, 0, stream>>>(ei, posIn, b3, xeA, nullp, xT, w1s, w2, w3s, b3s,
                                      wout, dstn, g1, be1, g2, be2, degIn, degOut,
                                      xeA, xeB, xeB, out, 0, 0);
    k_stage<<<NBLK, TPB, 0, stream>>>(ei, posIn, b3, xeB, nullp, xT, w1s, w2, w3s, b3s,
                                      wout, dstn, g1, be1, g2, be2, degIn, degOut,
                                      xeA, xeB, xeA, out, 0, 0);
    k_stage<<<NBLK, TPB, 0, stream>>>(ei, posIn, b3, xeA, nullp, xT, w1s, w2, w3s, b3s,
                                      wout, dstn, g1, be1, g2, be2, degIn, degOut,
                                      xeA, xeB, xeB, out, 1, 0);
}

// Round 8
// 175.626 us; speedup vs baseline: 1.2722x; 1.2722x over previous
//
#include <hip/hip_runtime.h>
#include <math.h>

// Problem constants (from reference setup_inputs)
#define BB 128        // batch
#define NN 2000       // nodes
#define EE 20000      // edges
#define CC 16         // channels
#define FUNC_LO 200   // func nodes: [200, 1800)
#define FUNC_HI 1800
#define OUT_LO 1800   // output nodes: [1800, 2000)
#define NFUNC 1600
#define EPSV 1e-5f
#define SS 40         // fixed slots per node per direction (Poisson(10): P(deg>40)~1e-15)
#define HP 129        // padded LDS stride

// ---------------- prep: slot assign + operand gather + transpose + zero out ---------
// One thread per edge does its own atomic slot-claim then immediately writes the
// gathered operands (slot value depends only on atomics among edges sharing a node;
// all other writes are thread-local -> single kernel, no internal dependencies).
__global__ __launch_bounds__(256) void k_prep(
    const float* __restrict__ x, const int* __restrict__ ei,
    const float* __restrict__ w1, const float* __restrict__ w3,
    const float* __restrict__ b3,
    int* __restrict__ degIn, int* __restrict__ degOut,
    int* __restrict__ posIn,
    float* __restrict__ xT, float* __restrict__ w1s, float* __restrict__ w3s,
    float* __restrict__ b3s, int* __restrict__ inoff, int* __restrict__ wout,
    int* __restrict__ dstn, float* __restrict__ out)
{
    int t = blockIdx.x * 256 + threadIdx.x;   // grid = NN*BB = 256000 threads
    if (t < EE) {
        int s = ei[t], d = ei[EE + t];
        int p = atomicAdd(&degIn[d], 1);
        int q = atomicAdd(&degOut[s], 1);
        int pi = d * SS + p, po = s * SS + q;
        posIn[t] = pi;
        inoff[pi] = s * BB;          // layer-0 input row = xT[src]
        wout[po]  = pi * BB;         // write target row = dst's in-slot
        dstn[po]  = d;
        b3s[po]   = b3[t];
        const float4* w1r = (const float4*)(w1 + (size_t)t * CC);
        float4*       w1d = (float4*)(w1s + (size_t)pi * CC);
        const float4* w3r = (const float4*)(w3 + (size_t)t * CC);
        float4*       w3d = (float4*)(w3s + (size_t)po * CC);
        #pragma unroll
        for (int i = 0; i < 4; i++) { w1d[i] = w1r[i]; w3d[i] = w3r[i]; }
    }
    if (t < NN * BB) {
        int b = t / NN, n = t - b * NN;
        xT[n * BB + b] = x[t];       // transpose x (B,N) -> xT (N,B), coalesced read
        out[t] = 0.0f;               // final output: zero everywhere (atomics add later)
    }
}

// ---------------- batchnorm + elu over a per-thread register column ----------------
// Thread b owns t[c] = h[c][b]. Stats per channel over 128 b via LDS tile.
__device__ __forceinline__ void bn_elu(float (&t)[CC],
                                       const float* __restrict__ g,
                                       const float* __restrict__ be,
                                       float* tile, float* part_s, float* part_ss,
                                       float* sc, float* sh, int b) {
    #pragma unroll
    for (int c = 0; c < CC; c++) tile[c * HP + b] = t[c];
    __syncthreads();
    {
        int c = b & 15, grp = b >> 4;          // 16 channels x 8 groups of 16 b
        float s = 0.f, ss = 0.f;
        #pragma unroll
        for (int i = 0; i < 16; i++) {
            float v = tile[c * HP + grp * 16 + i];
            s += v; ss += v * v;
        }
        part_s[grp * 16 + c] = s;
        part_ss[grp * 16 + c] = ss;
    }
    __syncthreads();
    if (b < CC) {
        float S = 0.f, SSm = 0.f;
        #pragma unroll
        for (int g8 = 0; g8 < 8; g8++) { S += part_s[g8 * 16 + b]; SSm += part_ss[g8 * 16 + b]; }
        float mean = S * (1.0f / BB);
        float var = SSm * (1.0f / BB) - mean * mean;
        float scale = rsqrtf(var + EPSV) * g[b];
        sc[b] = scale;
        sh[b] = be[b] - mean * scale;
    }
    __syncthreads();
    #pragma unroll
    for (int c = 0; c < CC; c++) {
        float u = t[c] * sc[c] + sh[c];
        t[c] = (u > 0.0f) ? u : (__expf(u) - 1.0f);
    }
}

// ---------------- constant rows for non-func-src edges (grid-stride) ----------------
// These rows are b3[e]+x0[e] at EVERY layer: write once into both xe buffers; edges
// landing on output nodes contribute straight into the final output.
__device__ __forceinline__ void fill_body(const int* __restrict__ ei,
    const int* __restrict__ posIn, const float* __restrict__ b3,
    const float* __restrict__ xT, float* __restrict__ xeA, float* __restrict__ xeB,
    float* __restrict__ out, int gtid, int gsize)
{
    for (int t = gtid; t < EE * BB; t += gsize) {
        int e = t >> 7, bb = t & 127;
        int s = ei[e];
        if (s >= FUNC_LO && s < FUNC_HI) continue;   // func src: handled by layers
        int d = ei[EE + e];
        float val = b3[e] + xT[s * BB + bb];
        if (d >= FUNC_LO && d < FUNC_HI) {
            int ro = posIn[e] * BB;
            xeA[ro + bb] = val;
            xeB[ro + bb] = val;
        } else if (d >= OUT_LO) {
            atomicAdd(&out[(size_t)bb * NN + d], val);
        }
    }
}

// ---------------- one stage: (optional fill) + one layer; 1 node / 128-thr block ----
// Phase A: acc[c] = sum_k xe_in[row(k)+b] * w1s[slot k][c]  (16 loads in flight ->
//          one vmcnt drain for the average node). Phase B: bn1+elu -> 16x16 matmul
//          (wave-uniform s_load weights) -> bn2+elu. Phase C: LDS-cached meta,
//          dot with w3s row, store row / atomic into final out.
__global__ __launch_bounds__(128) void k_stage(
    const int* __restrict__ ei, const int* __restrict__ posIn,
    const float* __restrict__ b3,
    const float* __restrict__ xe_in, const int* __restrict__ inoff, // inoff: layer 0 only
    const float* __restrict__ xT,
    const float* __restrict__ w1s, const float* __restrict__ w2,
    const float* __restrict__ w3s, const float* __restrict__ b3s,
    const int* __restrict__ wout, const int* __restrict__ dstn,
    const float* __restrict__ g1, const float* __restrict__ be1,
    const float* __restrict__ g2, const float* __restrict__ be2,
    const int* __restrict__ degIn, const int* __restrict__ degOut,
    float* __restrict__ xeA, float* __restrict__ xeB,
    float* __restrict__ xe_out, float* __restrict__ out, int lastFlag, int doFill)
{
    __shared__ float tile[CC * HP];          // 8.25 KB
    __shared__ float part_s[128], part_ss[128];
    __shared__ float sc[CC], sh[CC];
    __shared__ float l_b3[SS];
    __shared__ int   l_dst[SS], l_wout[SS];

    const int b = threadIdx.x;
    const int n = FUNC_LO + blockIdx.x;      // one func node per block
    const int base = n * SS;

    // cooperative Phase-C meta preload; ordered before use by the bn barriers
    if (b < SS) {
        l_b3[b]   = b3s[base + b];
        l_dst[b]  = dstn[base + b];
        l_wout[b] = wout[base + b];
    }

    int dIn = degIn[n];                      // wave-uniform -> s_load
    int dOut = degOut[n];
    float x0r = xT[n * BB + b];

    if (doFill)
        fill_body(ei, posIn, b3, xT, xeA, xeB, out,
                  blockIdx.x * 128 + b, NFUNC * 128);

    // ---- Phase A: weighted segment-sum over in-slots (16 loads in flight) ----
    float a[CC];
    #pragma unroll
    for (int c = 0; c < CC; c++) a[c] = 0.0f;

    for (int k0 = 0; k0 < dIn; k0 += 16) {
        float v[16];
        #pragma unroll
        for (int j = 0; j < 16; j++) {
            v[j] = 0.0f;
            if (k0 + j < dIn) {              // uniform predicate
                int ro = inoff ? inoff[base + k0 + j] : (base + k0 + j) * BB;
                v[j] = xe_in[ro + b];        // coalesced 512B row
            }
        }
        #pragma unroll
        for (int j = 0; j < 16; j++) {
            if (k0 + j < dIn) {
                const float* wr = &w1s[(size_t)(base + k0 + j) * CC]; // uniform -> s_load
                #pragma unroll
                for (int c = 0; c < CC; c++) a[c] += v[j] * wr[c];
            }
        }
    }

    // ---- bn1 + elu ----
    bn_elu(a, g1 + n * CC, be1 + n * CC, tile, part_s, part_ss, sc, sh, b);

    // ---- 16x16 matmul from registers, wave-uniform weights ----
    float h2[CC];
    #pragma unroll
    for (int d = 0; d < CC; d++) h2[d] = 0.0f;
    const float* w2n = w2 + n * (CC * CC);
    #pragma unroll
    for (int c = 0; c < CC; c++) {
        float av = a[c];
        #pragma unroll
        for (int d = 0; d < CC; d++) h2[d] += av * w2n[c * CC + d];
    }

    // ---- bn2 + elu ----
    bn_elu(h2, g2 + n * CC, be2 + n * CC, tile, part_s, part_ss, sc, sh, b);

    // ---- Phase C: push to live out-slots (meta from LDS) ----
    for (int q0 = 0; q0 < dOut; q0 += 4) {
        #pragma unroll
        for (int j = 0; j < 4; j++) {
            int q = q0 + j;
            if (q >= dOut) break;            // uniform
            int dn = l_dst[q];
            bool live = lastFlag ? (dn >= OUT_LO) : (dn >= FUNC_LO && dn < FUNC_HI);
            if (!live) continue;             // uniform: dead rows never read
            const float* wr = &w3s[(size_t)(base + q) * CC];   // uniform -> s_load
            float val = l_b3[q] + x0r;
            #pragma unroll
            for (int d = 0; d < CC; d++) val += h2[d] * wr[d];
            if (lastFlag) atomicAdd(&out[(size_t)b * NN + dn], val);
            else          xe_out[l_wout[q] + b] = val;
        }
    }
}

extern "C" void kernel_launch(void* const* d_in, const int* in_sizes, int n_in,
                              void* d_out, int out_size, void* d_ws, size_t ws_size,
                              hipStream_t stream) {
    const float* x   = (const float*)d_in[0];
    const float* w1  = (const float*)d_in[1];
    // d_in[2] = b1: cancels through batchnorm
    const float* w2  = (const float*)d_in[3];
    // d_in[4] = b2: cancels through batchnorm
    const float* w3  = (const float*)d_in[5];
    const float* b3  = (const float*)d_in[6];
    const float* g1  = (const float*)d_in[7];
    const float* be1 = (const float*)d_in[8];
    const float* g2  = (const float*)d_in[9];
    const float* be2 = (const float*)d_in[10];
    const int* ei    = (const int*)d_in[11];
    float* out = (float*)d_out;

    // workspace partition (fixed-stride slot layout, S=40) — ~95 MB total
    char* ws = (char*)d_ws;
    float* xT   = (float*)ws;  ws += (size_t)NN * BB * 4;            // 1.0 MB
    float* xeA  = (float*)ws;  ws += (size_t)NN * SS * BB * 4;       // 41 MB
    float* xeB  = (float*)ws;  ws += (size_t)NN * SS * BB * 4;       // 41 MB
    float* w1s  = (float*)ws;  ws += (size_t)NN * SS * CC * 4;       // 5.1 MB
    float* w3s  = (float*)ws;  ws += (size_t)NN * SS * CC * 4;       // 5.1 MB
    float* b3s  = (float*)ws;  ws += (size_t)NN * SS * 4;
    int* degIn  = (int*)ws;    ws += (size_t)NN * 4;                 // contiguous pair
    int* degOut = (int*)ws;    ws += (size_t)NN * 4;                 //   (one memset)
    int* posIn  = (int*)ws;    ws += (size_t)EE * 4;
    int* inoff  = (int*)ws;    ws += (size_t)NN * SS * 4;
    int* wout   = (int*)ws;    ws += (size_t)NN * SS * 4;
    int* dstn   = (int*)ws;    ws += (size_t)NN * SS * 4;

    hipMemsetAsync(degIn, 0, 2 * NN * sizeof(int), stream);
    k_prep<<<(NN * BB) / 256, 256, 0, stream>>>(x, ei, w1, w3, b3, degIn, degOut,
                                                posIn, xT, w1s, w3s, b3s,
                                                inoff, wout, dstn, out);

    const int* nullp = nullptr;
    k_stage<<<NFUNC, 128, 0, stream>>>(ei, posIn, b3, xT, inoff, xT, w1s, w2, w3s, b3s,
                                       wout, dstn, g1, be1, g2, be2, degIn, degOut,
                                       xeA, xeB, xeA, out, 0, 1);
    k_stage<<<NFUNC, 128, 0, stream>>>(ei, posIn, b3, xeA, nullp, xT, w1s, w2, w3s, b3s,
                                       wout, dstn, g1, be1, g2, be2, degIn, degOut,
                                       xeA, xeB, xeB, out, 0, 0);
    k_stage<<<NFUNC, 128, 0, stream>>>(ei, posIn, b3, xeB, nullp, xT, w1s, w2, w3s, b3s,
                                       wout, dstn, g1, be1, g2, be2, degIn, degOut,
                                       xeA, xeB, xeA, out, 0, 0);
    k_stage<<<NFUNC, 128, 0, stream>>>(ei, posIn, b3, xeA, nullp, xT, w1s, w2, w3s, b3s,
                                       wout, dstn, g1, be1, g2, be2, degIn, degOut,
                                       xeA, xeB, xeB, out, 1, 0);
}